// Round 13
// baseline (146.010 us; speedup 1.0000x reference)
//
#include <hip/hip_runtime.h>
#include <hip/hip_bf16.h>

typedef __attribute__((ext_vector_type(8))) short bf16x8;
typedef __attribute__((ext_vector_type(4))) float f32x4;

#define F_DIM 128
#define N_DIM 20000
#define M_DIM 128
#define NW 32                  // n per tile (128 B per f-row, line-aligned)
#define TILES_PER_B 625        // 20000/32
#define NT 40                  // tiles per block
#define GRID 250               // 250*40 = 10000 tiles
#define F32_BUF 32768          // one tile f32 stage (2 mats * 128f * 32n * 4B)
#define F32_MAT 16384
#define BF16_OFF 98304         // after 3 f32 buffers
#define BF16_MAT 8192

#define AS1 __attribute__((address_space(1)))
#define AS3 __attribute__((address_space(3)))

static __device__ inline unsigned short f2bf(float x) {
    union { float f; unsigned u; } v; v.f = x;
    unsigned r = v.u + 0x7fffu + ((v.u >> 16) & 1u);   // RNE
    return (unsigned short)(r >> 16);
}

static __device__ inline unsigned cvt_pk_bf16(float lo, float hi) {
    unsigned r;
    asm("v_cvt_pk_bf16_f32 %0, %1, %2" : "=v"(r) : "v"(lo), "v"(hi));
    return r;
}

// ---------------------------------------------------------------------------
// Kernel 1: fold resize into projections; bf16 in MFMA fragment order.
// ---------------------------------------------------------------------------
__global__ __launch_bounds__(256) void precompute_mats(
    const float* __restrict__ W_rs,   // (128, 384)
    const float* __restrict__ W_e2m,  // (128, 128)
    const float* __restrict__ W_n2m,  // (128, 128)
    unsigned short* __restrict__ wsA,
    unsigned short* __restrict__ wsB)
{
    int idx = blockIdx.x * 256 + threadIdx.x;   // 0..16383
    int k = idx >> 7;
    int f = idx & 127;
    float a = 0.f, b = 0.f;
    for (int m = 0; m < 128; ++m) {
        a += W_rs[k * 384 + m]       * W_e2m[m * 128 + f];
        b += W_rs[k * 384 + 128 + m] * W_n2m[m * 128 + f];
    }
    int mt = k >> 4, row = k & 15;
    int c = f >> 5, kk = f & 31;
    int lane = ((kk >> 3) << 4) | row;
    int j = kk & 7;
    int off = ((mt * 4 + c) * 64 + lane) * 8 + j;
    wsA[off] = f2bf(a);
    wsB[off] = f2bf(b);
}

// ---------------------------------------------------------------------------
// Kernel 2: per-(b,k) bias.
// ---------------------------------------------------------------------------
__global__ __launch_bounds__(128) void precompute_bias(
    const float* __restrict__ W_rs,
    const float* __restrict__ h_v,
    const float* __restrict__ b_e2m,
    const float* __restrict__ b_n2m,
    const float* __restrict__ b_rs,
    const float* __restrict__ W_n2m,
    float* __restrict__ bias)
{
    __shared__ float nv_s[128];
    int b = blockIdx.x;
    int t = threadIdx.x;
    {
        float nv = b_n2m[t];
        for (int f = 0; f < 128; ++f)
            nv += h_v[b * 128 + f] * W_n2m[t * 128 + f];
        nv_s[t] = nv;
    }
    __syncthreads();
    {
        float acc = b_rs[t];
        for (int m = 0; m < 128; ++m) {
            acc += W_rs[t * 384 + m]       * b_e2m[m];
            acc += W_rs[t * 384 + 128 + m] * b_n2m[m];
            acc += W_rs[t * 384 + 256 + m] * nv_s[m];
        }
        bias[b * 128 + t] = acc;
    }
}

// ---------------------------------------------------------------------------
// Kernel 3: depth-3 pipelined GEMM with PAIRED DMA issue (adjacency probe).
// 512 thr (8 waves, mt = wave). Even iters issue tiles (t+2, t+3) with
// row-interleaved instruction pairs -> each f-row's two adjacent 128-B lines
// requested back-to-back (256-B DRAM row-hits). 3 f32 buffers (k -> buf k%3),
// single bf16 buffer, operand-swapped MFMA, vectorized stores.
// vmcnt ledger (in-order retirement; membership-exact):
//   t==0: [bias 1][batch 8] -> 9 ; odd t: [B3 1][stores 2][bias 1] -> 4 ;
//   even t>=2: [st 2][bias 1][st 2][bias 1][batch 8] -> 14.
// ---------------------------------------------------------------------------
__global__ __launch_bounds__(512, 1) void msg_main(
    const float* __restrict__ e_wv,
    const float* __restrict__ h_w,
    const unsigned short* __restrict__ wsA,
    const unsigned short* __restrict__ wsB,
    const float* __restrict__ bias,
    float* __restrict__ out)
{
    __shared__ __align__(16) unsigned char smem[114688];  // 3x32KB f32 + 16KB bf16

    int tid = threadIdx.x;
    int w   = tid >> 6;        // 0..7, owns mt = w
    int l   = tid & 63;
    unsigned base = (unsigned)blockIdx.x * NT;

    // ---- preload weight fragments (loop-invariant, 32 VGPR)
    const bf16x8* Af = (const bf16x8*)wsA;
    const bf16x8* Bf = (const bf16x8*)wsB;
    bf16x8 A[4], B[4];
#pragma unroll
    for (int c = 0; c < 4; ++c) {
        A[c] = Af[(w * 4 + c) * 64 + l];
        B[c] = Bf[(w * 4 + c) * 64 + l];
    }

    int fl = l >> 3, p = l & 7;
    int ln = l & 15, g = l >> 4;

    // one DMA instruction: unit = w*4+i; mat = unit>>4; rows 8*(unit&15)..+7
    auto dma_unit = [&](unsigned tau, unsigned bufidx, int i) {
        unsigned bb = tau / TILES_PER_B;
        unsigned n0 = (tau - bb * TILES_PER_B) * NW;
        int unit = w * 4 + i;
        int mat = unit >> 4;          // wave-uniform
        int rg  = unit & 15;
        int f   = rg * 8 + fl;
        int gx  = (f ^ (f >> 3)) & 7;
        int col = (p ^ gx) << 2;
        const float* src = (mat ? h_w : e_wv)
            + (size_t)bb * (F_DIM * (size_t)N_DIM) + n0 + (size_t)f * N_DIM + col;
        unsigned char* dst = smem + bufidx * F32_BUF + mat * F32_MAT + rg * 1024;
        __builtin_amdgcn_global_load_lds((const AS1 unsigned*)src,
                                         (AS3 unsigned*)dst, 16, 0, 0);
    };

    // paired issue: same rows of tauA/tauB adjacent in the instruction stream
    auto issue_pair = [&](unsigned tauA, unsigned bufA, unsigned tauB, unsigned bufB) {
#pragma unroll
        for (int i = 0; i < 4; ++i) {
            dma_unit(tauA, bufA, i);
            dma_unit(tauB, bufB, i);
        }
    };

    auto dummy_pair = [&](unsigned bufA, unsigned bufB) {
#pragma unroll
        for (int i = 0; i < 4; ++i) {
            int unit = w * 4 + i;
            int mat = unit >> 4;
            int rg  = unit & 15;
            unsigned char* dA = smem + bufA * F32_BUF + mat * F32_MAT + rg * 1024;
            unsigned char* dB = smem + bufB * F32_BUF + mat * F32_MAT + rg * 1024;
            __builtin_amdgcn_global_load_lds((const AS1 unsigned*)e_wv,
                                             (AS3 unsigned*)dA, 16, 0, 0);
            __builtin_amdgcn_global_load_lds((const AS1 unsigned*)h_w,
                                             (AS3 unsigned*)dB, 16, 0, 0);
        }
    };

    // transform tile -> bf16 frag layout (identical formulas to verified R12)
    auto transform = [&](unsigned bufidx) {
        int mat = tid >> 8;
        int u   = tid & 255;
        int fp  = u >> 2;        // 0..63
        int qh  = u & 3;
        const unsigned char* fsrc = smem + bufidx * F32_BUF + mat * F32_MAT;
        unsigned char* bdst = smem + BF16_OFF + mat * BF16_MAT;
        int f0 = 2 * fp, f1 = 2 * fp + 1;
        int g0 = (f0 ^ (f0 >> 3)) & 7, g1 = (f1 ^ (f1 >> 3)) & 7;
#pragma unroll
        for (int j = 0; j < 2; ++j) {
            int q = qh * 2 + j;
            f32x4 a = *(const f32x4*)(fsrc + f0 * 128 + ((q ^ g0) << 4));
            f32x4 c = *(const f32x4*)(fsrc + f1 * 128 + ((q ^ g1) << 4));
#pragma unroll
            for (int e = 0; e < 4; ++e) {
                int n = q * 4 + e;
                unsigned pk = cvt_pk_bf16(a[e], c[e]);   // lo=f0, hi=f1
                unsigned off = (unsigned)(n * 256) +
                               (((unsigned)(fp * 4)) ^ ((unsigned)((n & 7) << 4)));
                *(unsigned*)(bdst + off) = pk;
            }
        }
    };

    // ---- prologue: paired DMA of tiles 0,1 -> bufs 0,1; transform tile 0
    issue_pair(base + 0, 0, base + 1, 1);
    asm volatile("s_waitcnt vmcnt(1)" ::: "memory");   // tile 0 landed
    __builtin_amdgcn_s_barrier();
    transform(0);
    asm volatile("s_waitcnt lgkmcnt(0)" ::: "memory");
    __builtin_amdgcn_s_barrier();

    unsigned rbase = (unsigned)(ln * 256);
    unsigned rx = (unsigned)((ln & 7) << 4);
    const unsigned char* ldse = smem + BF16_OFF;
    const unsigned char* ldsw = smem + BF16_OFF + BF16_MAT;

#pragma unroll 1
    for (int t = 0; t < NT; ++t) {
        unsigned tau = base + t;
        unsigned bb = tau / TILES_PER_B;
        unsigned n0 = (tau - bb * TILES_PER_B) * NW;

        // per-lane scalar bias for this tile's k-row
        float bvc = bias[bb * 128 + w * 16 + ln];

        // even iters: paired issue of tiles t+2, t+3 (dummy at t = NT-2)
        if ((t & 1) == 0) {
            if (t + 3 < NT)
                issue_pair(base + t + 2, (unsigned)((t + 2) % 3),
                           base + t + 3, (unsigned)((t + 3) % 3));
            else
                dummy_pair((unsigned)((t + 2) % 3), (unsigned)((t + 3) % 3));
        }

        // compute(t), operand-swapped: acc = mfma(X, W, acc)
        f32x4 acc[2];
        acc[0] = (f32x4)(0.f);
        acc[1] = (f32x4)(0.f);
#pragma unroll
        for (int c = 0; c < 4; ++c) {
            unsigned fbyte = (unsigned)((c * 32 + g * 8) * 2) ^ rx;
#pragma unroll
            for (int ns = 0; ns < 2; ++ns) {
                bf16x8 xe = *(const bf16x8*)(ldse + ns * 4096 + rbase + fbyte);
                bf16x8 xw = *(const bf16x8*)(ldsw + ns * 4096 + rbase + fbyte);
                acc[ns] = __builtin_amdgcn_mfma_f32_16x16x32_bf16(xe, A[c], acc[ns], 0, 0, 0);
                acc[ns] = __builtin_amdgcn_mfma_f32_16x16x32_bf16(xw, B[c], acc[ns], 0, 0, 0);
            }
        }

        // counted wait for DMA(t+1); membership-exact per ledger above
        if (t == 0)      { asm volatile("s_waitcnt vmcnt(9)"  ::: "memory"); }
        else if (t & 1)  { asm volatile("s_waitcnt vmcnt(4)"  ::: "memory"); }
        else             { asm volatile("s_waitcnt vmcnt(14)" ::: "memory"); }
        asm volatile("s_waitcnt lgkmcnt(0)" ::: "memory");
        __builtin_amdgcn_s_barrier();

        if (t < NT - 1) transform((unsigned)((t + 1) % 3));
        asm volatile("s_waitcnt lgkmcnt(0)" ::: "memory");
        __builtin_amdgcn_s_barrier();

        // store(t): transposed D -> lane owns 4 consecutive n at fixed k
        float* O = out + (size_t)bb * (M_DIM * (size_t)N_DIM) + n0;
        int k = w * 16 + ln;
#pragma unroll
        for (int ns = 0; ns < 2; ++ns) {
            f32x4 v = acc[ns];
            v[0] += bvc; v[1] += bvc; v[2] += bvc; v[3] += bvc;
            *(f32x4*)(O + (size_t)k * N_DIM + ns * 16 + g * 4) = v;
        }
    }

    // drain outstanding DMAs before endpgm (LDS reuse hazard)
    asm volatile("s_waitcnt vmcnt(0)" ::: "memory");
}

extern "C" void kernel_launch(void* const* d_in, const int* in_sizes, int n_in,
                              void* d_out, int out_size, void* d_ws, size_t ws_size,
                              hipStream_t stream) {
    const float* h_w   = (const float*)d_in[0];
    const float* h_v   = (const float*)d_in[1];
    const float* e_wv  = (const float*)d_in[2];
    const float* W_e2m = (const float*)d_in[3];
    const float* b_e2m = (const float*)d_in[4];
    const float* W_n2m = (const float*)d_in[5];
    const float* b_n2m = (const float*)d_in[6];
    const float* W_rs  = (const float*)d_in[7];
    const float* b_rs  = (const float*)d_in[8];
    float* out = (float*)d_out;

    unsigned short* wsA = (unsigned short*)d_ws;                     // 32 KB
    unsigned short* wsB = wsA + 128 * 128;                           // 32 KB
    float* bias = (float*)((char*)d_ws + 65536);                     // 8 KB

    precompute_mats<<<64, 256, 0, stream>>>(W_rs, W_e2m, W_n2m, wsA, wsB);
    precompute_bias<<<16, 128, 0, stream>>>(W_rs, h_v, b_e2m, b_n2m, b_rs, W_n2m, bias);
    msg_main<<<GRID, 512, 0, stream>>>(e_wv, h_w, wsA, wsB, bias, out);
}